// Round 4
// baseline (156.384 us; speedup 1.0000x reference)
//
#include <hip/hip_runtime.h>
#include <cstdint>

// Problem constants
#define C_IN   128
#define C_OUT  256
#define KK     1152      // C_IN * 9 (im2col K)
#define NPIX   4096      // 64*64
#define BS     16
#define M_ROWS 65536     // BS * NPIX
#define QMAXF  127.0f

typedef int v4i __attribute__((ext_vector_type(4)));

// ---- workspace layout (bytes) ----
// qW' (tap-major permuted) @ OFF_QW; w_part aliases it (read before qW' write).
#define OFF_QW    75497472
#define OFF_SCALE 75792384
#define OFF_QMUL  75796992
#define OFF_APART 75801600
#define OFF_SCAL  75843072

// K-A: fused act_scale (blocks 0..1023) + w_scale (blocks 1024..1103).
__global__ void k_prep(const float* __restrict__ x, const float* __restrict__ wgt,
                       float* __restrict__ act_part, float* __restrict__ w_part) {
    const int tid = threadIdx.x;
    if (blockIdx.x >= 1024) {
        int t = blockIdx.x - 1024;        // 0..79
        int j = (t % 5) * 256 + tid;
        int s = t / 5;                    // 0..15
        if (j >= KK) return;
        const float* p = wgt + (size_t)s * 16 * KK + j;
        float m = 0.f;
#pragma unroll
        for (int i = 0; i < 16; i++) m = fmaxf(m, fabsf(p[(size_t)i * KK]));
        w_part[s * KK + j] = m;
        return;
    }
    const int c = blockIdx.x >> 3, s = blockIdx.x & 7;
    float m[9];
#pragma unroll
    for (int i = 0; i < 9; i++) m[i] = 0.f;
    for (int p = tid; p < 2 * NPIX; p += 256) {
        int b = s * 2 + (p >> 12);
        int hw = p & 4095;
        int h = hw >> 6, w = hw & 63;
        float v = fabsf(x[b * (C_IN * NPIX) + c * NPIX + hw]);
        bool rr[3] = { h <= 62, true, h >= 1 };
        bool cc[3] = { w <= 62, true, w >= 1 };
#pragma unroll
        for (int i = 0; i < 3; i++)
#pragma unroll
            for (int jq = 0; jq < 3; jq++)
                m[i * 3 + jq] = fmaxf(m[i * 3 + jq], (rr[i] && cc[jq]) ? v : 0.f);
    }
    __shared__ float sm[9][4];
    int lane = tid & 63, wid = tid >> 6;
#pragma unroll
    for (int i = 0; i < 9; i++) {
        float v = m[i];
        for (int off = 32; off > 0; off >>= 1) v = fmaxf(v, __shfl_down(v, off));
        if (lane == 0) sm[i][wid] = v;
    }
    __syncthreads();
    if (tid < 9) {
        float v = fmaxf(fmaxf(sm[tid][0], sm[tid][1]), fmaxf(sm[tid][2], sm[tid][3]));
        act_part[s * KK + c * 9 + tid] = v;
    }
}

// K-B: scales + s_x + s_w + qmul. Single block, 1024 threads.
__global__ void k_scales(const float* __restrict__ act_part, const float* __restrict__ w_part,
                         float* __restrict__ scale, float* __restrict__ qmul,
                         float* __restrict__ scalars) {
    const int tid = threadIdx.x;
    float sc_local[2] = {1.f, 1.f};
    float mx = 0.f, mw = 0.f;
#pragma unroll
    for (int t = 0; t < 2; t++) {
        int j = tid + t * 1024;
        if (j < KK) {
            float a = 0.f;
#pragma unroll
            for (int s = 0; s < 8; s++) a = fmaxf(a, act_part[s * KK + j]);
            float wv = 0.f;
#pragma unroll
            for (int s = 0; s < 16; s++) wv = fmaxf(wv, w_part[s * KK + j]);
            float sc = sqrtf(a) / sqrtf(wv);
            if (sc == 0.f) sc = 1.0f;
            scale[j] = sc;
            sc_local[t] = sc;
            mx = fmaxf(mx, a / sc);    // exact: max_r |cols[r,j]/sc| == fl(act/sc)
            mw = fmaxf(mw, wv * sc);   // exact: max_i |w2[i,j]*sc|  == fl(wsc*sc)
        }
    }
    __shared__ float smx[16], smw[16];
    __shared__ float s_x_sh;
    int lane = tid & 63, wid = tid >> 6;
    for (int off = 32; off > 0; off >>= 1) {
        mx = fmaxf(mx, __shfl_down(mx, off));
        mw = fmaxf(mw, __shfl_down(mw, off));
    }
    if (lane == 0) { smx[wid] = mx; smw[wid] = mw; }
    __syncthreads();
    if (tid == 0) {
        float a = 0.f, b = 0.f;
        for (int i = 0; i < 16; i++) { a = fmaxf(a, smx[i]); b = fmaxf(b, smw[i]); }
        float s_x = a / QMAXF; if (s_x == 0.f) s_x = 1.f;
        float s_w = b / QMAXF; if (s_w == 0.f) s_w = 1.f;
        scalars[0] = s_x; scalars[1] = s_w; scalars[2] = s_x * s_w;
        s_x_sh = s_x;
    }
    __syncthreads();
    float s_x = s_x_sh;
#pragma unroll
    for (int t = 0; t < 2; t++) {
        int j = tid + t * 1024;
        if (j < KK) qmul[j] = 1.0f / (sc_local[t] * s_x);
    }
}

// K-C: quantize weights into TAP-MAJOR layout: qWp[m][tap*128 + c] = fq(w[m][c*9+tap]).
__global__ void k_quant_w(const float* __restrict__ wgt, const float* __restrict__ scale,
                          const float* __restrict__ scalars, signed char* __restrict__ qWp) {
    int idx = blockIdx.x * 256 + threadIdx.x;   // < 294912, coalesced WRITE
    int m  = (unsigned)idx / KK;
    int kp = idx - m * KK;
    int tap = kp >> 7, c = kp & 127;
    int j = c * 9 + tap;                        // original k index
    float s_w = scalars[1];
    float t = wgt[m * KK + j] * scale[j];
    float q = rintf(t / s_w);
    q = fminf(fmaxf(q, -QMAXF), QMAXF);
    qWp[idx] = (signed char)(int)q;
}

// ---- produce tap TP of Bs from row regs XV into buffer BSP ----
// Pack via v_perm_b32 (3 perms / 4 elems vs and/shl/or chains). Row-invalid
// (vertical pad) is handled for free: the guarded x-row load zero-fills XV, so
// q==0. Horizontal pad: the single edge lane writes the pad row; zero via 4
// cndmasks on the packed words (not 16 on elements).
// No clamp: s_x is constructed as max_j(amax_j/sc_j)/127 => |v*qm| <= ~127.
#define PRODUCE(TP, XV, BSP)                                                    \
    do {                                                                        \
        const int jj_ = (TP) % 3, sh_ = jj_ - 1;                                \
        int n_ = lane - sh_;                                                    \
        bool valid_ = (unsigned)n_ < 64u;                                       \
        int wrow_ = valid_ ? n_ : (sh_ == -1 ? 0 : 63);                         \
        const float* qmt_ = qm + (TP) * 128 + c0;                               \
        int pk_[4];                                                             \
        _Pragma("unroll")                                                       \
        for (int d4 = 0; d4 < 4; d4++) {                                        \
            int q0_ = (int)rintf(XV[d4 * 4 + 0] * qmt_[d4 * 4 + 0]);            \
            int q1_ = (int)rintf(XV[d4 * 4 + 1] * qmt_[d4 * 4 + 1]);            \
            int q2_ = (int)rintf(XV[d4 * 4 + 2] * qmt_[d4 * 4 + 2]);            \
            int q3_ = (int)rintf(XV[d4 * 4 + 3] * qmt_[d4 * 4 + 3]);            \
            unsigned t0_ = __builtin_amdgcn_perm((unsigned)q1_, (unsigned)q0_, 0x0c0c0400u); \
            unsigned t1_ = __builtin_amdgcn_perm((unsigned)q3_, (unsigned)q2_, 0x0c0c0400u); \
            int w_ = (int)__builtin_amdgcn_perm(t1_, t0_, 0x05040100u);         \
            pk_[d4] = valid_ ? w_ : 0;                                          \
        }                                                                       \
        *(v4i*)((BSP) + wrow_ * 128 + ((wv ^ (wrow_ & 7)) * 16)) =              \
            (v4i){pk_[0], pk_[1], pk_[2], pk_[3]};                              \
    } while (0)

// ---- MFMA one tap from buffer BSP; prefetch A frags for tap TP+1 ----
#define MFMA_TAP(TP, BSP)                                                       \
    do {                                                                        \
        if ((TP) < 8) {                                                         \
            _Pragma("unroll")                                                   \
            for (int h = 0; h < 2; h++)                                         \
                _Pragma("unroll")                                               \
                for (int mt = 0; mt < 2; mt++)                                  \
                    afn[h][mt] = *(const v4i*)(aBase + (size_t)mt * 16 * KK +   \
                                               ((TP) + 1) * 128 + h * 64);      \
        }                                                                       \
        _Pragma("unroll")                                                       \
        for (int h = 0; h < 2; h++) {                                           \
            const int q4_ = h * 4 + (lane >> 4);                                \
            v4i bf_[4];                                                         \
            _Pragma("unroll")                                                   \
            for (int nt = 0; nt < 4; nt++) {                                    \
                int rb_ = nt * 16 + (lane & 15);                                \
                bf_[nt] = *(const v4i*)((BSP) + rb_ * 128 + ((q4_ ^ (rb_ & 7)) * 16)); \
            }                                                                   \
            _Pragma("unroll")                                                   \
            for (int mt = 0; mt < 2; mt++)                                      \
                _Pragma("unroll")                                               \
                for (int nt = 0; nt < 4; nt++)                                  \
                    acc[mt][nt] = __builtin_amdgcn_mfma_i32_16x16x64_i8(        \
                        af[h][mt], bf_[nt], acc[mt][nt], 0, 0, 0);              \
        }                                                                       \
        if ((TP) < 8) {                                                         \
            _Pragma("unroll")                                                   \
            for (int h = 0; h < 2; h++)                                         \
                _Pragma("unroll")                                               \
                for (int mt = 0; mt < 2; mt++) af[h][mt] = afn[h][mt];          \
        }                                                                       \
    } while (0)

// K-D: FUSED quant+GEMM v5 — GROUP-PHASED. Block = 256(M) x 64(N), 512 thr,
// 8 waves, acc[2][4]. LDS holds a kh-GROUP (3 taps, 24 KB) double-buffered:
// phase = { produce group g+1 -> buf^1 ; MFMA 3 taps of group g ; barrier }.
// Barriers drop 10 -> 4; 48 MFMAs between barriers (LDS first-use latency
// amortized 3x; produce VALU overlaps the independent MFMA section in-phase).
// x rows: g0->xr (prologue, guarded), g1->xrn (prologue), g2->xr reloaded
// right after g0's produce (slack = 1 barrier + full phase).
// XCD swizzle: contiguous 128-tile runs per XCD for x-row L2 locality (R3:
// FETCH 55->20 MB).
__global__ __launch_bounds__(512, 4) void k_gemm(const signed char* __restrict__ qWp,
                                                 const float* __restrict__ x,
                                                 const float* __restrict__ qmul,
                                                 const float* __restrict__ scalars,
                                                 const float* __restrict__ bias,
                                                 float* __restrict__ out) {
    __shared__ __align__(16) signed char Bs[2][3][64 * 128];  // 2 x 24 KB
    __shared__ float qm[KK];                                  // permuted qmul [tap][c]
    const int tid = threadIdx.x;
    const int lane = tid & 63, wv = tid >> 6;              // 8 waves
    const int bid = blockIdx.x;
    const int swz = (bid & 7) * 128 + (bid >> 3);          // bijective (1024 % 8 == 0)
    const int b  = swz >> 6;
    const int oh = swz & 63;
    const float* xb = x + (size_t)b * (C_IN * NPIX);
    const int c0 = wv * 16;                                // thread's channel chunk

    for (int i = tid; i < KK; i += 512) {
        int tap = i >> 7, c = i & 127;
        qm[i] = qmul[c * 9 + tap];
    }

    // A addressing: row = wv*32 + mt*16 + (lane&15); 16B chunk (lane>>4) of K=64 half h
    const signed char* aBase = qWp + (size_t)(wv * 32 + (lane & 15)) * KK + (lane >> 4) * 16;

    v4i acc[2][4];
#pragma unroll
    for (int i = 0; i < 2; i++)
#pragma unroll
        for (int jq = 0; jq < 4; jq++) acc[i][jq] = (v4i){0, 0, 0, 0};

    // x rows: group0 (ih = oh-1, guarded) -> xr ; group1 (ih = oh) -> xrn
    float xr[16], xrn[16];
    {
        const bool ok = oh >= 1;
        const float* s = xb + (oh - 1) * 64 + lane;
#pragma unroll
        for (int d = 0; d < 16; d++) xr[d] = ok ? s[(size_t)(c0 + d) * NPIX] : 0.f;
    }
    {
        const float* sp = xb + oh * 64 + lane;
#pragma unroll
        for (int d = 0; d < 16; d++) xrn[d] = sp[(size_t)(c0 + d) * NPIX];
    }
    // A fragments for tap 0
    v4i af[2][2], afn[2][2];
#pragma unroll
    for (int h = 0; h < 2; h++)
#pragma unroll
        for (int mt = 0; mt < 2; mt++)
            af[h][mt] = *(const v4i*)(aBase + (size_t)mt * 16 * KK + 0 * 128 + h * 64);

    __syncthreads();   // qm ready

    // prologue: produce group 0 (taps 0-2) from xr
    PRODUCE(0, xr, (signed char*)Bs[0][0]);
    PRODUCE(1, xr, (signed char*)Bs[0][1]);
    PRODUCE(2, xr, (signed char*)Bs[0][2]);

    // reload xr <- group2 row (ih = oh+1, guarded); consumed in phase 1
    {
        const bool ok = (oh + 1) < 64;
        const float* sp = xb + (oh + 1) * 64 + lane;
#pragma unroll
        for (int d = 0; d < 16; d++) xr[d] = ok ? sp[(size_t)(c0 + d) * NPIX] : 0.f;
    }

    __syncthreads();   // group 0 published

    // ---- phase 0: produce group 1 ; MFMA group 0 ----
    PRODUCE(3, xrn, (signed char*)Bs[1][0]);
    PRODUCE(4, xrn, (signed char*)Bs[1][1]);
    PRODUCE(5, xrn, (signed char*)Bs[1][2]);
    MFMA_TAP(0, (const signed char*)Bs[0][0]);
    MFMA_TAP(1, (const signed char*)Bs[0][1]);
    MFMA_TAP(2, (const signed char*)Bs[0][2]);
    __syncthreads();   // group 1 published; group 0 buffer free

    // ---- phase 1: produce group 2 ; MFMA group 1 ----
    PRODUCE(6, xr, (signed char*)Bs[0][0]);
    PRODUCE(7, xr, (signed char*)Bs[0][1]);
    PRODUCE(8, xr, (signed char*)Bs[0][2]);
    MFMA_TAP(3, (const signed char*)Bs[1][0]);
    MFMA_TAP(4, (const signed char*)Bs[1][1]);
    MFMA_TAP(5, (const signed char*)Bs[1][2]);
    __syncthreads();   // group 2 published

    // ---- phase 2: MFMA group 2 ----
    MFMA_TAP(6, (const signed char*)Bs[0][0]);
    MFMA_TAP(7, (const signed char*)Bs[0][1]);
    MFMA_TAP(8, (const signed char*)Bs[0][2]);

    const float ssp = scalars[2];
    const int quad = lane >> 4, col = lane & 15;
    float bv[2][4];
#pragma unroll
    for (int mt = 0; mt < 2; mt++)
#pragma unroll
        for (int rg = 0; rg < 4; rg++)
            bv[mt][rg] = bias[wv * 32 + mt * 16 + quad * 4 + rg];

    float* obase = out + ((size_t)b * C_OUT) * NPIX + oh * 64;
#pragma unroll
    for (int mt = 0; mt < 2; mt++) {
#pragma unroll
        for (int nt = 0; nt < 4; nt++) {
            int n = nt * 16 + col;
#pragma unroll
            for (int rg = 0; rg < 4; rg++) {
                int m = wv * 32 + mt * 16 + quad * 4 + rg;   // c_out
                obase[(size_t)m * NPIX + n] = (float)acc[mt][nt][rg] * ssp + bv[mt][rg];
            }
        }
    }
}

extern "C" void kernel_launch(void* const* d_in, const int* in_sizes, int n_in,
                              void* d_out, int out_size, void* d_ws, size_t ws_size,
                              hipStream_t stream) {
    const float* x    = (const float*)d_in[0];
    const float* wgt  = (const float*)d_in[1];
    const float* bias = (const float*)d_in[2];
    float* out = (float*)d_out;

    char* ws = (char*)d_ws;
    signed char* qWp = (signed char*)(ws + OFF_QW);
    float* w_part    = (float*)(ws + OFF_QW);     // aliases qWp (read before qWp write)
    float* scale     = (float*)(ws + OFF_SCALE);
    float* qmul      = (float*)(ws + OFF_QMUL);
    float* act_part  = (float*)(ws + OFF_APART);
    float* scalars   = (float*)(ws + OFF_SCAL);

    k_prep<<<1104, 256, 0, stream>>>(x, wgt, act_part, w_part);
    k_scales<<<1, 1024, 0, stream>>>(act_part, w_part, scale, qmul, scalars);
    k_quant_w<<<(C_OUT * KK) / 256, 256, 0, stream>>>(wgt, scale, scalars, qWp);
    k_gemm<<<BS * 64, 512, 0, stream>>>(qWp, x, qmul, scalars, bias, out);
}

// Round 5
// 147.904 us; speedup vs baseline: 1.0573x; 1.0573x over previous
//
#include <hip/hip_runtime.h>
#include <cstdint>

// Problem constants
#define C_IN   128
#define C_OUT  256
#define KK     1152      // C_IN * 9 (im2col K)
#define NPIX   4096      // 64*64
#define BS     16
#define M_ROWS 65536     // BS * NPIX
#define QMAXF  127.0f

typedef int v4i __attribute__((ext_vector_type(4)));

// ---- workspace layout (bytes) ----
// qW' (tap-major permuted) @ OFF_QW; w_part aliases it (read before qW' write).
#define OFF_QW    75497472
#define OFF_SCALE 75792384
#define OFF_QMUL  75796992
#define OFF_APART 75801600
#define OFF_SCAL  75843072

// K-A: fused act_scale (blocks 0..1023) + w_scale (blocks 1024..1103).
// Act part vectorized: float4 loads (8 iters of 256 threads covers 2 images' channel c).
__global__ void k_prep(const float* __restrict__ x, const float* __restrict__ wgt,
                       float* __restrict__ act_part, float* __restrict__ w_part) {
    const int tid = threadIdx.x;
    if (blockIdx.x >= 1024) {
        int t = blockIdx.x - 1024;        // 0..79
        int j = (t % 5) * 256 + tid;
        int s = t / 5;                    // 0..15
        if (j >= KK) return;
        const float* p = wgt + (size_t)s * 16 * KK + j;
        float m = 0.f;
#pragma unroll
        for (int i = 0; i < 16; i++) m = fmaxf(m, fabsf(p[(size_t)i * KK]));
        w_part[s * KK + j] = m;
        return;
    }
    const int c = blockIdx.x >> 3, s = blockIdx.x & 7;
    float m[9];
#pragma unroll
    for (int i = 0; i < 9; i++) m[i] = 0.f;
    const float4* xp4 = (const float4*)(x + (size_t)(s * 2) * (C_IN * NPIX) + (size_t)c * NPIX);
    const int img4 = C_IN * NPIX / 4;     // float4 stride between the 2 images
    for (int v = tid; v < 2048; v += 256) {
        int half = v >> 10;               // image 0/1 of this s-slice
        int hw4  = v & 1023;              // float4 index within 4096 pixels
        int h  = hw4 >> 4;                // 16 float4 per 64-pix row
        int w4 = (hw4 & 15) * 4;
        float4 f = xp4[half * img4 + hw4];
        bool rr[3] = { h <= 62, true, h >= 1 };
#pragma unroll
        for (int e = 0; e < 4; e++) {
            int w = w4 + e;
            float vv = fabsf(e == 0 ? f.x : e == 1 ? f.y : e == 2 ? f.z : f.w);
            bool cc[3] = { w <= 62, true, w >= 1 };
#pragma unroll
            for (int i = 0; i < 3; i++)
#pragma unroll
                for (int jq = 0; jq < 3; jq++)
                    m[i * 3 + jq] = fmaxf(m[i * 3 + jq], (rr[i] && cc[jq]) ? vv : 0.f);
        }
    }
    __shared__ float sm[9][4];
    int lane = tid & 63, wid = tid >> 6;
#pragma unroll
    for (int i = 0; i < 9; i++) {
        float v = m[i];
        for (int off = 32; off > 0; off >>= 1) v = fmaxf(v, __shfl_down(v, off));
        if (lane == 0) sm[i][wid] = v;
    }
    __syncthreads();
    if (tid < 9) {
        float v = fmaxf(fmaxf(sm[tid][0], sm[tid][1]), fmaxf(sm[tid][2], sm[tid][3]));
        act_part[s * KK + c * 9 + tid] = v;
    }
}

// K-B: scales + s_x + s_w + qmul. Single block, 1024 threads.
__global__ void k_scales(const float* __restrict__ act_part, const float* __restrict__ w_part,
                         float* __restrict__ scale, float* __restrict__ qmul,
                         float* __restrict__ scalars) {
    const int tid = threadIdx.x;
    float sc_local[2] = {1.f, 1.f};
    float mx = 0.f, mw = 0.f;
#pragma unroll
    for (int t = 0; t < 2; t++) {
        int j = tid + t * 1024;
        if (j < KK) {
            float a = 0.f;
#pragma unroll
            for (int s = 0; s < 8; s++) a = fmaxf(a, act_part[s * KK + j]);
            float wv = 0.f;
#pragma unroll
            for (int s = 0; s < 16; s++) wv = fmaxf(wv, w_part[s * KK + j]);
            float sc = sqrtf(a) / sqrtf(wv);
            if (sc == 0.f) sc = 1.0f;
            scale[j] = sc;
            sc_local[t] = sc;
            mx = fmaxf(mx, a / sc);    // exact: max_r |cols[r,j]/sc| == fl(act/sc)
            mw = fmaxf(mw, wv * sc);   // exact: max_i |w2[i,j]*sc|  == fl(wsc*sc)
        }
    }
    __shared__ float smx[16], smw[16];
    __shared__ float s_x_sh;
    int lane = tid & 63, wid = tid >> 6;
    for (int off = 32; off > 0; off >>= 1) {
        mx = fmaxf(mx, __shfl_down(mx, off));
        mw = fmaxf(mw, __shfl_down(mw, off));
    }
    if (lane == 0) { smx[wid] = mx; smw[wid] = mw; }
    __syncthreads();
    if (tid == 0) {
        float a = 0.f, b = 0.f;
        for (int i = 0; i < 16; i++) { a = fmaxf(a, smx[i]); b = fmaxf(b, smw[i]); }
        float s_x = a / QMAXF; if (s_x == 0.f) s_x = 1.f;
        float s_w = b / QMAXF; if (s_w == 0.f) s_w = 1.f;
        scalars[0] = s_x; scalars[1] = s_w; scalars[2] = s_x * s_w;
        s_x_sh = s_x;
    }
    __syncthreads();
    float s_x = s_x_sh;
#pragma unroll
    for (int t = 0; t < 2; t++) {
        int j = tid + t * 1024;
        if (j < KK) qmul[j] = 1.0f / (sc_local[t] * s_x);
    }
}

// K-C: quantize weights into TAP-MAJOR layout: qWp[m][tap*128 + c] = fq(w[m][c*9+tap]).
__global__ void k_quant_w(const float* __restrict__ wgt, const float* __restrict__ scale,
                          const float* __restrict__ scalars, signed char* __restrict__ qWp) {
    int idx = blockIdx.x * 256 + threadIdx.x;   // < 294912, coalesced WRITE
    int m  = (unsigned)idx / KK;
    int kp = idx - m * KK;
    int tap = kp >> 7, c = kp & 127;
    int j = c * 9 + tap;                        // original k index
    float s_w = scalars[1];
    float t = wgt[m * KK + j] * scale[j];
    float q = rintf(t / s_w);
    q = fminf(fmaxf(q, -QMAXF), QMAXF);
    qWp[idx] = (signed char)(int)q;
}

// ---- produce tap TP into buffer BSP (4-wave version: thread covers 32 channels
// as two 16-ch halves; chunk index = wv*2 + ha in [0,8)). Pack via v_perm_b32.
// Vertical pad free (guarded x loads zero-fill xr); horizontal pad via 4 cndmasks
// on packed words. No clamp: s_x construction bounds |v*qm| <= ~127.
#define PRODUCE(TP, BSP)                                                        \
    do {                                                                        \
        const int jj_ = (TP) % 3, sh_ = jj_ - 1;                                \
        int n_ = lane - sh_;                                                    \
        bool valid_ = (unsigned)n_ < 64u;                                       \
        int wrow_ = valid_ ? n_ : (sh_ == -1 ? 0 : 63);                         \
        _Pragma("unroll")                                                       \
        for (int ha = 0; ha < 2; ha++) {                                        \
            const float* qmt_ = qm + (TP) * 128 + c0 + ha * 16;                 \
            const float* xv_ = xr + ha * 16;                                    \
            int pk_[4];                                                         \
            _Pragma("unroll")                                                   \
            for (int d4 = 0; d4 < 4; d4++) {                                    \
                int q0_ = (int)rintf(xv_[d4 * 4 + 0] * qmt_[d4 * 4 + 0]);       \
                int q1_ = (int)rintf(xv_[d4 * 4 + 1] * qmt_[d4 * 4 + 1]);       \
                int q2_ = (int)rintf(xv_[d4 * 4 + 2] * qmt_[d4 * 4 + 2]);       \
                int q3_ = (int)rintf(xv_[d4 * 4 + 3] * qmt_[d4 * 4 + 3]);       \
                unsigned t0_ = __builtin_amdgcn_perm((unsigned)q1_, (unsigned)q0_, 0x0c0c0400u); \
                unsigned t1_ = __builtin_amdgcn_perm((unsigned)q3_, (unsigned)q2_, 0x0c0c0400u); \
                int w_ = (int)__builtin_amdgcn_perm(t1_, t0_, 0x05040100u);     \
                pk_[d4] = valid_ ? w_ : 0;                                      \
            }                                                                   \
            *(v4i*)((BSP) + wrow_ * 128 + (((wv * 2 + ha) ^ (wrow_ & 7)) * 16)) = \
                (v4i){pk_[0], pk_[1], pk_[2], pk_[3]};                          \
        }                                                                       \
    } while (0)

// K-D: FUSED quant+GEMM v6 — MORE INDEPENDENT BLOCKS. Grid 2048 = (b,oh,m-half),
// block = 256 thr (4 waves), each block does a 128(M) x 64(N) tile. Per CU: 4
// independent barrier domains x 4 waves (vs 2 x 8) at the same 16-wave budget ->
// produce/MFMA phases of different blocks overlap instead of lockstepping.
// Cost: produce duplicated per m-half (VALU x~1.8 aggregate), x re-read x2 (L2).
// Regs capped at 128 (launch_bounds(256,4)): af loaded at PHASE START (hidden
// under produce, no afn), x rows reloaded on-demand at taps 2/5 (L2-hot: the
// sibling m-half + adjacent-oh blocks on the same XCD read identical rows).
__global__ __launch_bounds__(256, 4) void k_gemm(const signed char* __restrict__ qWp,
                                                 const float* __restrict__ x,
                                                 const float* __restrict__ qmul,
                                                 const float* __restrict__ scalars,
                                                 const float* __restrict__ bias,
                                                 float* __restrict__ out) {
    __shared__ __align__(16) signed char Bs[2][64 * 128];  // 2 x 8 KB
    __shared__ float qm[KK];                               // permuted qmul [tap][c]
    const int tid = threadIdx.x;
    const int lane = tid & 63, wv = tid >> 6;              // 4 waves
    const int raw = blockIdx.x;
    const int swz = (raw & 7) * 256 + (raw >> 3);          // bijective (2048 % 8 == 0)
    const int b  = swz >> 7;                               // each XCD: 2 whole images
    const int oh = (swz >> 1) & 63;
    const int hm = swz & 1;                                // m-half (adjacent dispatch)
    const float* xb = x + (size_t)b * (C_IN * NPIX);
    const int c0 = wv * 32;                                // thread's 32-channel chunk

    for (int i = tid; i < KK; i += 256) {
        int tap = i >> 7, c = i & 127;
        qm[i] = qmul[c * 9 + tap];
    }

    // A addressing: row = hm*128 + wv*32 + mt*16 + (lane&15); chunk (lane>>4) of K-half h
    const signed char* aBase = qWp + (size_t)(hm * 128 + wv * 32 + (lane & 15)) * KK + (lane >> 4) * 16;

    v4i acc[2][4];
#pragma unroll
    for (int i = 0; i < 2; i++)
#pragma unroll
        for (int jq = 0; jq < 4; jq++) acc[i][jq] = (v4i){0, 0, 0, 0};

    // x rows for group 0 (ih = oh-1, guarded): 32 channels
    float xr[32];
    {
        const bool ok = oh >= 1;
        const float* s = xb + (oh - 1) * 64 + lane;
#pragma unroll
        for (int d = 0; d < 32; d++) xr[d] = ok ? s[(size_t)(c0 + d) * NPIX] : 0.f;
    }
    v4i af[2][2];

    __syncthreads();   // qm ready

#pragma unroll
    for (int t = 0; t < 9; t++) {
        signed char* bsp = (signed char*)Bs[t & 1];

        // ---- af loads for THIS tap at phase start (L2-hot; hidden under produce) ----
#pragma unroll
        for (int h = 0; h < 2; h++)
#pragma unroll
            for (int mt = 0; mt < 2; mt++)
                af[h][mt] = *(const v4i*)(aBase + (size_t)mt * 16 * KK + t * 128 + h * 64);

        // ---- produce Bs(tap t) from xr ----
        PRODUCE(t, bsp);

        // ---- reload xr for next kh-group (after last use by produce) ----
        if (t == 2) {      // group 1: ih = oh (always valid)
            const float* sp = xb + oh * 64 + lane;
#pragma unroll
            for (int d = 0; d < 32; d++) xr[d] = sp[(size_t)(c0 + d) * NPIX];
        }
        if (t == 5) {      // group 2: ih = oh+1 (guarded)
            const bool ok = (oh + 1) < 64;
            const float* sp = xb + (oh + 1) * 64 + lane;
#pragma unroll
            for (int d = 0; d < 32; d++) xr[d] = ok ? sp[(size_t)(c0 + d) * NPIX] : 0.f;
        }

        __syncthreads();   // Bs(t) published; dbuf covers WAR vs tap t-1 readers

        // ---- MFMA: two K=64 substeps ----
#pragma unroll
        for (int h = 0; h < 2; h++) {
            const int q4 = h * 4 + (lane >> 4);
            v4i bf[4];
#pragma unroll
            for (int nt = 0; nt < 4; nt++) {
                int rb = nt * 16 + (lane & 15);
                bf[nt] = *(const v4i*)(bsp + rb * 128 + ((q4 ^ (rb & 7)) * 16));
            }
#pragma unroll
            for (int mt = 0; mt < 2; mt++)
#pragma unroll
                for (int nt = 0; nt < 4; nt++)
                    acc[mt][nt] = __builtin_amdgcn_mfma_i32_16x16x64_i8(af[h][mt], bf[nt], acc[mt][nt], 0, 0, 0);
        }

        if (t < 8) __syncthreads();   // MFMA(t) done reading Bs[t&1] before produce(t+1)... 
        // NOTE: produce(t+1) writes Bs[(t+1)&1], NOT Bs[t&1]; this barrier instead
        // protects Bs[(t+1)&1] (written next phase) against THIS phase's readers of
        // Bs[(t-1)&1]... with 2-deep buffering the pre-MFMA barrier alone suffices
        // only if no wave runs 2 taps ahead; this barrier enforces that.
    }

    const float ssp = scalars[2];
    const int quad = lane >> 4, col = lane & 15;
    float bv[2][4];
#pragma unroll
    for (int mt = 0; mt < 2; mt++)
#pragma unroll
        for (int rg = 0; rg < 4; rg++)
            bv[mt][rg] = bias[hm * 128 + wv * 32 + mt * 16 + quad * 4 + rg];

    float* obase = out + ((size_t)b * C_OUT) * NPIX + oh * 64;
#pragma unroll
    for (int mt = 0; mt < 2; mt++) {
#pragma unroll
        for (int nt = 0; nt < 4; nt++) {
            int n = nt * 16 + col;
#pragma unroll
            for (int rg = 0; rg < 4; rg++) {
                int m = hm * 128 + wv * 32 + mt * 16 + quad * 4 + rg;   // c_out
                obase[(size_t)m * NPIX + n] = (float)acc[mt][nt][rg] * ssp + bv[mt][rg];
            }
        }
    }
}

extern "C" void kernel_launch(void* const* d_in, const int* in_sizes, int n_in,
                              void* d_out, int out_size, void* d_ws, size_t ws_size,
                              hipStream_t stream) {
    const float* x    = (const float*)d_in[0];
    const float* wgt  = (const float*)d_in[1];
    const float* bias = (const float*)d_in[2];
    float* out = (float*)d_out;

    char* ws = (char*)d_ws;
    signed char* qWp = (signed char*)(ws + OFF_QW);
    float* w_part    = (float*)(ws + OFF_QW);     // aliases qWp (read before qWp write)
    float* scale     = (float*)(ws + OFF_SCALE);
    float* qmul      = (float*)(ws + OFF_QMUL);
    float* act_part  = (float*)(ws + OFF_APART);
    float* scalars   = (float*)(ws + OFF_SCAL);

    k_prep<<<1104, 256, 0, stream>>>(x, wgt, act_part, w_part);
    k_scales<<<1, 1024, 0, stream>>>(act_part, w_part, scale, qmul, scalars);
    k_quant_w<<<(C_OUT * KK) / 256, 256, 0, stream>>>(wgt, scale, scalars, qWp);
    k_gemm<<<2 * BS * 64, 256, 0, stream>>>(qWp, x, qmul, scalars, bias, out);
}

// Round 6
// 142.586 us; speedup vs baseline: 1.0968x; 1.0373x over previous
//
#include <hip/hip_runtime.h>
#include <cstdint>

// Problem constants
#define C_IN   128
#define C_OUT  256
#define KK     1152      // C_IN * 9 (im2col K)
#define NPIX   4096      // 64*64
#define BS     16
#define M_ROWS 65536     // BS * NPIX
#define QMAXF  127.0f

typedef int v4i __attribute__((ext_vector_type(4)));

// ---- workspace layout (bytes) ----
// w_part moved to offset 0 (de-aliased from qWp: k_scalequant reads w_part and
// writes qWp in the SAME kernel -> overlap would race across blocks).
// High-water mark unchanged vs prior rounds.
#define OFF_WPART 0          // 16*1152*4 = 73728 B
#define OFF_QW    75497472   // 294912 B
#define OFF_SCALE 75792384
#define OFF_QMUL  75796992
#define OFF_APART 75801600   // 8*1152*4 = 36864 B -> ends 75838464
#define OFF_SCAL  75843072

// K-A: fused act_scale (blocks 0..1023) + w_scale (blocks 1024..1103).
// Act: float4 loads; 3 col-class maxes per float4 (vall / excl-col0 / excl-col63)
// + row-class predication => ~3x less VALU than per-element 9-way select.
__global__ void k_prep(const float* __restrict__ x, const float* __restrict__ wgt,
                       float* __restrict__ act_part, float* __restrict__ w_part) {
    const int tid = threadIdx.x;
    if (blockIdx.x >= 1024) {
        int t = blockIdx.x - 1024;        // 0..79
        int j = (t % 5) * 256 + tid;
        int s = t / 5;                    // 0..15
        if (j >= KK) return;
        const float* p = wgt + (size_t)s * 16 * KK + j;
        float m = 0.f;
#pragma unroll
        for (int i = 0; i < 16; i++) m = fmaxf(m, fabsf(p[(size_t)i * KK]));
        w_part[s * KK + j] = m;
        return;
    }
    const int c = blockIdx.x >> 3, s = blockIdx.x & 7;
    float m[9];
#pragma unroll
    for (int i = 0; i < 9; i++) m[i] = 0.f;
    const float4* xp4 = (const float4*)(x + (size_t)(s * 2) * (C_IN * NPIX) + (size_t)c * NPIX);
    const int img4 = C_IN * NPIX / 4;     // float4 stride between the 2 images
    for (int v = tid; v < 2048; v += 256) {
        int half = v >> 10;               // image 0/1 of this s-slice
        int hw4  = v & 1023;              // float4 index within 4096 pixels
        int h   = hw4 >> 4;               // 16 float4 per 64-pix row
        int w4i = hw4 & 15;               // f4 index within row
        float4 f = xp4[half * img4 + hw4];
        float ax = fabsf(f.x), ay = fabsf(f.y), az = fabsf(f.z), aw = fabsf(f.w);
        float vall = fmaxf(fmaxf(ax, ay), fmaxf(az, aw));
        float vnoF = (w4i == 0)  ? fmaxf(fmaxf(ay, az), aw) : vall;  // excl col 0
        float vnoL = (w4i == 15) ? fmaxf(fmaxf(ax, ay), az) : vall;  // excl col 63
        bool r0 = (h <= 62), r2 = (h >= 1);
        // m[i*3+jq]: row class i in {h<=62, all, h>=1}, col class jq in {w<=62, all, w>=1}
        m[0] = fmaxf(m[0], r0 ? vnoL : 0.f);
        m[1] = fmaxf(m[1], r0 ? vall : 0.f);
        m[2] = fmaxf(m[2], r0 ? vnoF : 0.f);
        m[3] = fmaxf(m[3], vnoL);
        m[4] = fmaxf(m[4], vall);
        m[5] = fmaxf(m[5], vnoF);
        m[6] = fmaxf(m[6], r2 ? vnoL : 0.f);
        m[7] = fmaxf(m[7], r2 ? vall : 0.f);
        m[8] = fmaxf(m[8], r2 ? vnoF : 0.f);
    }
    __shared__ float sm[9][4];
    int lane = tid & 63, wid = tid >> 6;
#pragma unroll
    for (int i = 0; i < 9; i++) {
        float v = m[i];
        for (int off = 32; off > 0; off >>= 1) v = fmaxf(v, __shfl_down(v, off));
        if (lane == 0) sm[i][wid] = v;
    }
    __syncthreads();
    if (tid < 9) {
        float v = fmaxf(fmaxf(sm[tid][0], sm[tid][1]), fmaxf(sm[tid][2], sm[tid][3]));
        act_part[s * KK + c * 9 + tid] = v;
    }
}

// K-B2: FUSED scales + weight-quant. Grid 257 blocks x 256 thr -> replaces the
// single-block k_scales (255 CUs idle, serial-latency-bound) + k_quant_w launch.
// EVERY block redundantly computes the scale table from the L2-hot partials
// (110 KB; deterministic fp => bit-identical across blocks; no grid sync).
// Block 0 writes qmul+scalars for k_gemm; blocks 1..256 quantize W-row (bid-1)
// into tap-major qWp[m][tap*128+c].
__global__ void k_scalequant(const float* __restrict__ act_part, const float* __restrict__ w_part,
                             const float* __restrict__ wgt,
                             float* __restrict__ qmul, float* __restrict__ scalars,
                             signed char* __restrict__ qWp) {
    const int tid = threadIdx.x;
    __shared__ float ssc[KK];      // scale table (4.6 KB)
    __shared__ float red[16];
    __shared__ float s_sw, s_sx;
    float mx = 0.f, mw = 0.f;
    for (int j = tid; j < KK; j += 256) {
        float a = 0.f;
#pragma unroll
        for (int s = 0; s < 8; s++) a = fmaxf(a, act_part[s * KK + j]);
        float wv = 0.f;
#pragma unroll
        for (int s = 0; s < 16; s++) wv = fmaxf(wv, w_part[s * KK + j]);
        float sc = sqrtf(a) / sqrtf(wv);
        if (sc == 0.f) sc = 1.0f;
        ssc[j] = sc;
        mx = fmaxf(mx, a / sc);    // exact: max_r |cols[r,j]/sc| == fl(act/sc)
        mw = fmaxf(mw, wv * sc);   // exact: max_i |w2[i,j]*sc|  == fl(wsc*sc)
    }
    int lane = tid & 63, wid = tid >> 6;
    for (int off = 32; off > 0; off >>= 1) {
        mx = fmaxf(mx, __shfl_down(mx, off));
        mw = fmaxf(mw, __shfl_down(mw, off));
    }
    if (lane == 0) { red[wid] = mx; red[8 + wid] = mw; }
    __syncthreads();
    if (tid == 0) {
        float a = fmaxf(fmaxf(red[0], red[1]), fmaxf(red[2], red[3]));
        float b = fmaxf(fmaxf(red[8], red[9]), fmaxf(red[10], red[11]));
        float s_x = a / QMAXF; if (s_x == 0.f) s_x = 1.f;
        float s_w = b / QMAXF; if (s_w == 0.f) s_w = 1.f;
        s_sx = s_x; s_sw = s_w;
    }
    __syncthreads();
    const int bid = blockIdx.x;
    if (bid == 0) {
        const float s_x = s_sx, s_w = s_sw;
        if (tid == 0) { scalars[0] = s_x; scalars[1] = s_w; scalars[2] = s_x * s_w; }
        for (int j = tid; j < KK; j += 256) qmul[j] = 1.0f / (ssc[j] * s_x);
        return;
    }
    // quantize W row m = bid-1 into tap-major layout
    const int m = bid - 1;
    const float s_w = s_sw;
    for (int kp = tid; kp < KK; kp += 256) {
        int tap = kp >> 7, c = kp & 127;
        int j = c * 9 + tap;
        float t = wgt[(size_t)m * KK + j] * ssc[j];
        float q = rintf(t / s_w);
        q = fminf(fmaxf(q, -QMAXF), QMAXF);
        qWp[(size_t)m * KK + kp] = (signed char)(int)q;
    }
}

// K-D: FUSED quant+GEMM — R3 schedule (best measured: 53.1 us) + R4 perm-pack
// produce (proven: VALU 27->23%). Block = 256(M) x 64(N = 1 out row), 512 thr,
// 8 waves (32-row M-strips, acc[2][4] in AGPR). x rows loaded ONCE per kh-group
// (prefetched a group ahead); kw shift realized as the ds_write ROW address.
// Bs double-buffered, XOR 16B-chunk swizzle, ONE barrier per tap. A-fragments
// global->VGPR (L2-hot), prefetched one tap ahead. XCD swizzle: contiguous
// 128-tile runs per XCD (R3: FETCH 55->20 MB). No clamp in produce: s_x is
// constructed as max_j(amax_j/sc_j)/127 => rintf lands in [-127,127].
__global__ __launch_bounds__(512, 4) void k_gemm(const signed char* __restrict__ qWp,
                                                 const float* __restrict__ x,
                                                 const float* __restrict__ qmul,
                                                 const float* __restrict__ scalars,
                                                 const float* __restrict__ bias,
                                                 float* __restrict__ out) {
    __shared__ __align__(16) signed char Bs[2][64 * 128];  // 2 x 8 KB
    __shared__ float qm[KK];                               // permuted qmul [tap][c]
    const int tid = threadIdx.x;
    const int lane = tid & 63, wv = tid >> 6;              // 8 waves
    const int bid = blockIdx.x;
    const int swz = (bid & 7) * 128 + (bid >> 3);          // bijective (1024 % 8 == 0)
    const int b  = swz >> 6;
    const int oh = swz & 63;
    const float* xb = x + (size_t)b * (C_IN * NPIX);
    const int c0 = wv * 16;                                // thread's channel chunk

    for (int i = tid; i < KK; i += 512) {
        int tap = i >> 7, c = i & 127;
        qm[i] = qmul[c * 9 + tap];
    }

    // A addressing: row = wv*32 + mt*16 + (lane&15); 16B chunk (lane>>4) of K=64 half h
    const signed char* aBase = qWp + (size_t)(wv * 32 + (lane & 15)) * KK + (lane >> 4) * 16;

    v4i acc[2][4];
#pragma unroll
    for (int i = 0; i < 2; i++)
#pragma unroll
        for (int jq = 0; jq < 4; jq++) acc[i][jq] = (v4i){0, 0, 0, 0};

    // preload: x row for kh-group 0 (ih = oh-1, guarded zero-fill), A frags tap 0
    float xr[16], xrn[16];
    {
        const bool ok = oh >= 1;
        const float* s = xb + (oh - 1) * 64 + lane;
#pragma unroll
        for (int d = 0; d < 16; d++) xr[d] = ok ? s[(size_t)(c0 + d) * NPIX] : 0.f;
    }
    v4i af[2][2], afn[2][2];
#pragma unroll
    for (int h = 0; h < 2; h++)
#pragma unroll
        for (int mt = 0; mt < 2; mt++)
            af[h][mt] = *(const v4i*)(aBase + (size_t)mt * 16 * KK + 0 * 128 + h * 64);

    __syncthreads();   // qm ready

#pragma unroll
    for (int tap = 0; tap < 9; tap++) {
        const int g  = (tap * 11) >> 5;      // kh = tap/3
        const int jj = tap - g * 3;          // kw
        const int s  = jj - 1;               // horizontal shift -1/0/+1
        signed char* bsp = (signed char*)Bs[tap & 1];

        // ---- produce Bs(tap): thread's value belongs to output pixel n = lane - s.
        // Vertical pad is free (guarded x loads zero-fill xr); horizontal pad via
        // 4 cndmasks on packed words; pack via v_perm_b32.
        {
            int n = lane - s;
            bool valid = (unsigned)n < 64u;
            int wrow = valid ? n : (s == -1 ? 0 : 63);   // edge lane fills the zero row
            const float* qmt = qm + tap * 128 + c0;
            int pk[4];
#pragma unroll
            for (int d4 = 0; d4 < 4; d4++) {
                int q0 = (int)rintf(xr[d4 * 4 + 0] * qmt[d4 * 4 + 0]);
                int q1 = (int)rintf(xr[d4 * 4 + 1] * qmt[d4 * 4 + 1]);
                int q2 = (int)rintf(xr[d4 * 4 + 2] * qmt[d4 * 4 + 2]);
                int q3 = (int)rintf(xr[d4 * 4 + 3] * qmt[d4 * 4 + 3]);
                unsigned t0 = __builtin_amdgcn_perm((unsigned)q1, (unsigned)q0, 0x0c0c0400u);
                unsigned t1 = __builtin_amdgcn_perm((unsigned)q3, (unsigned)q2, 0x0c0c0400u);
                int w = (int)__builtin_amdgcn_perm(t1, t0, 0x05040100u);
                pk[d4] = valid ? w : 0;
            }
            *(v4i*)(bsp + wrow * 128 + ((wv ^ (wrow & 7)) * 16)) = (v4i){pk[0], pk[1], pk[2], pk[3]};
        }

        // ---- prefetch next kh-group's x row (issued once per group, ~3-tap window) ----
        if (jj == 0 && g < 2) {
            const bool ok = (unsigned)(oh + g) < 64u;
            const float* sp = xb + (oh + g) * 64 + lane;
#pragma unroll
            for (int d = 0; d < 16; d++) xrn[d] = ok ? sp[(size_t)(c0 + d) * NPIX] : 0.f;
        }

        __syncthreads();   // Bs(tap) ready; dbuf covers WAR vs tap-2 reads

        // ---- prefetch A fragments for tap+1 (hidden behind MFMA + next produce) ----
        if (tap < 8) {
#pragma unroll
            for (int h = 0; h < 2; h++)
#pragma unroll
                for (int mt = 0; mt < 2; mt++)
                    afn[h][mt] = *(const v4i*)(aBase + (size_t)mt * 16 * KK + (tap + 1) * 128 + h * 64);
        }

        // ---- MFMA: two K=64 substeps ----
#pragma unroll
        for (int h = 0; h < 2; h++) {
            const int q4 = h * 4 + (lane >> 4);
            v4i bf[4];
#pragma unroll
            for (int nt = 0; nt < 4; nt++) {
                int rb = nt * 16 + (lane & 15);
                bf[nt] = *(const v4i*)(bsp + rb * 128 + ((q4 ^ (rb & 7)) * 16));
            }
#pragma unroll
            for (int mt = 0; mt < 2; mt++)
#pragma unroll
                for (int nt = 0; nt < 4; nt++)
                    acc[mt][nt] = __builtin_amdgcn_mfma_i32_16x16x64_i8(af[h][mt], bf[nt], acc[mt][nt], 0, 0, 0);
        }

        // rotate prefetch regs (renamed under full unroll)
        if (tap < 8) {
#pragma unroll
            for (int h = 0; h < 2; h++)
#pragma unroll
                for (int mt = 0; mt < 2; mt++) af[h][mt] = afn[h][mt];
        }
        if (jj == 2 && g < 2) {
#pragma unroll
            for (int d = 0; d < 16; d++) xr[d] = xrn[d];
        }
    }

    const float ssp = scalars[2];
    const int quad = lane >> 4, col = lane & 15;
    float bv[2][4];
#pragma unroll
    for (int mt = 0; mt < 2; mt++)
#pragma unroll
        for (int rg = 0; rg < 4; rg++)
            bv[mt][rg] = bias[wv * 32 + mt * 16 + quad * 4 + rg];

    float* obase = out + ((size_t)b * C_OUT) * NPIX + oh * 64;
#pragma unroll
    for (int mt = 0; mt < 2; mt++) {
#pragma unroll
        for (int nt = 0; nt < 4; nt++) {
            int n = nt * 16 + col;
#pragma unroll
            for (int rg = 0; rg < 4; rg++) {
                int m = wv * 32 + mt * 16 + quad * 4 + rg;   // c_out
                obase[(size_t)m * NPIX + n] = (float)acc[mt][nt][rg] * ssp + bv[mt][rg];
            }
        }
    }
}

extern "C" void kernel_launch(void* const* d_in, const int* in_sizes, int n_in,
                              void* d_out, int out_size, void* d_ws, size_t ws_size,
                              hipStream_t stream) {
    const float* x    = (const float*)d_in[0];
    const float* wgt  = (const float*)d_in[1];
    const float* bias = (const float*)d_in[2];
    float* out = (float*)d_out;

    char* ws = (char*)d_ws;
    float* w_part    = (float*)(ws + OFF_WPART);   // de-aliased (offset 0)
    signed char* qWp = (signed char*)(ws + OFF_QW);
    float* qmul      = (float*)(ws + OFF_QMUL);
    float* act_part  = (float*)(ws + OFF_APART);
    float* scalars   = (float*)(ws + OFF_SCAL);

    k_prep<<<1104, 256, 0, stream>>>(x, wgt, act_part, w_part);
    k_scalequant<<<257, 256, 0, stream>>>(act_part, w_part, wgt, qmul, scalars, qWp);
    k_gemm<<<BS * 64, 512, 0, stream>>>(qWp, x, qmul, scalars, bias, out);
}